// Round 10
// baseline (466.890 us; speedup 1.0000x reference)
//
#include <hip/hip_runtime.h>
#include <math.h>

// Problem constants
constexpr int BQ   = 2048;
constexpr int D    = 256;
constexpr int NMEM = 100000;
constexpr int TOPK = 16;
constexpr int NCLS = 1000;
constexpr float TAU = 0.2f;
constexpr float LOGIT_SCALE = 20.0f;

// fp8(e4m3) GEMM (K=256) for candidate SELECTION only, via 2x-rate
// mfma_scale_f32_32x32x64_f8f6f4 (scales pinned to 1.0 = e8m0 0x7f).
// Round-6/7 lessons: (a) 64x64-per-wave can't hold A+acc in regs (r7 spill:
// WRITE_SIZE 29->89 MB); (b) the barrier-coupled LDS pipeline keeps a
// ~2300 cyc/iter residual even with counted vmcnt (r6). This round:
// 32x64-per-wave (acc 32 + Areg 32), NO LDS, NO barriers — B streams
// global->register with a 1-step-ahead double buffer. The chunk's B slice
// is 0.8 MB -> L2-resident; 4x wm-redundant reads cost ~45 us of L2 BW
// aggregate (36 TB/s), not HBM. B k-byte-order identical to r7 (validated).
constexpr int KTOT = 256;        // k-elements (= bytes in fp8)
constexpr int TM   = 128;
constexpr int TN   = 128;
constexpr int CTILES = 25;
constexpr int CHUNK  = TN * CTILES;               // 3200
constexpr int NCH    = 32;                        // 32*3200 = 102400 >= 100000
constexpr int RBLK   = BQ / TM;                   // 16
constexpr int NBLK   = RBLK * NCH;                // 512 = 2 blocks/CU exact
constexpr float XSCALE = 16.0f;
constexpr float INV_XS = 0.0625f;
constexpr float THR    = 3.0f;   // candidate floor (mean ~136/row above it)
constexpr float THRS   = 48.0f;  // THR * XSCALE (raw acc scale)
constexpr int CAP    = 512;      // per-row candidate cap
constexpr int MSEL   = 64;       // refinement superset target
constexpr int SELCAP = 96;
constexpr float NEG  = -3.0e38f;

using i32x4  = __attribute__((ext_vector_type(4))) int;
using i32x8  = __attribute__((ext_vector_type(8))) int;
using f32x16 = __attribute__((ext_vector_type(16))) float;

// f32 -> OCP e4m3 (RNE, clamp to 448, flush subnormals — inputs pre-scaled
// so the flush region carries negligible mass).
__device__ __forceinline__ unsigned f2e4m3(float f) {
    const unsigned u = __float_as_uint(f);
    const unsigned s = (u >> 24) & 0x80u;
    const int e = (int)((u >> 23) & 0xff);
    int te = e - 120;                          // e4m3 exponent field (bias 7)
    if (te <= 0) return s;                     // flush tiny
    const unsigned m = u & 0x7fffffu;
    const unsigned r = m + 0x7ffffu + ((m >> 20) & 1u);
    unsigned keep;
    if (r & 0x800000u) { ++te; keep = 0; } else keep = (r >> 20) & 7u;
    if (te >= 16 || (te == 15 && keep == 7)) return s | 0x7eu;  // clamp 448
    return s | ((unsigned)te << 3) | keep;
}

// ---------------------------------------------------------------------------
// Phase A: standardize + L2-normalize; emit A1 = e4m3(16*x_hat), XN = f32
// x_hat, and zero the per-row candidate counters.
// ---------------------------------------------------------------------------
__global__ __launch_bounds__(256) void knn_prep(
    const float* __restrict__ x, const float* __restrict__ mean,
    const float* __restrict__ stdv, unsigned char* __restrict__ A1,
    float* __restrict__ XN, int* __restrict__ cnt)
{
    const int row = blockIdx.x;
    const int t = threadIdx.x;                       // feature index, D==256
    float v = (x[row * D + t] - mean[t]) / stdv[t];
    float s = v * v;
    #pragma unroll
    for (int off = 32; off > 0; off >>= 1) s += __shfl_down(s, off, 64);
    __shared__ float wsum[4];
    __shared__ float nrm;
    const int lane = t & 63, wid = t >> 6;
    if (lane == 0) wsum[wid] = s;
    __syncthreads();
    if (t == 0) {
        nrm = fmaxf(sqrtf(wsum[0] + wsum[1] + wsum[2] + wsum[3]), 1e-6f);
        cnt[row] = 0;
    }
    __syncthreads();
    const float xnv = v / nrm;
    A1[(size_t)row * KTOT + t] = (unsigned char)f2e4m3(xnv * XSCALE);
    XN[(size_t)row * D + t] = xnv;
}

// ---------------------------------------------------------------------------
// Phase A2: mem_features -> B1 = e4m3(mem); 8 rows/block, float4 -> 8 bytes
// ---------------------------------------------------------------------------
__global__ __launch_bounds__(256) void knn_convb(
    const float* __restrict__ mem, unsigned char* __restrict__ B1)
{
    const int tid = threadIdx.x;
    const int rloc = tid >> 5, t = tid & 31;         // 32 threads per row
    const long n = (long)blockIdx.x * 8 + rloc;
    if (n >= NMEM) return;
    const float* src = mem + n * D + t * 8;
    const float4 v0 = *(const float4*)(src);
    const float4 v1 = *(const float4*)(src + 4);
    const float f[8] = {v0.x, v0.y, v0.z, v0.w, v1.x, v1.y, v1.z, v1.w};
    unsigned long long pk = 0;
    #pragma unroll
    for (int i = 0; i < 8; ++i)
        pk |= (unsigned long long)f2e4m3(f[i]) << (8 * i);
    *(unsigned long long*)(B1 + n * KTOT + t * 8) = pk;
}

// ---------------------------------------------------------------------------
// Phase B: barrier-free, LDS-free MX-fp8 GEMM. 8 waves/block (512 thr),
// each wave owns 32 rows x 64 cols (1x2 tiles of 32x32).
//  * Areg[4] (32 VGPR): this wave's 32 A-rows, all K, loaded once from L2.
//  * B: global->reg, 1-step-ahead double buffer (Bb/Bc, statically indexed
//    via fully-unrolled ks body — rule #20). Per step: 4 dwordx4 loads
//    (one 64-B line per B-row, both kb halves) + 2 MFMA. Compiler emits
//    the counted vmcnt waits (pure-register pipeline, nothing to alias).
//  * (512,4): 128-reg cap; est ~115 used. TRIPWIRE: WRITE_SIZE > 40 MB
//    => spill => revert to r6 LDS-pipeline kernel.
//  * chunk-exclusive XCD map: XCD x owns 4 chunks (B slice 0.8 MB,
//    L2-resident); 16 rowblocks share it.
// ---------------------------------------------------------------------------
__global__ __launch_bounds__(512, 4) void knn_gemm_topk(
    const unsigned char* __restrict__ A1, const unsigned char* __restrict__ B1,
    int* __restrict__ cnt, uint2* __restrict__ cand_buf)
{
    const int tid  = threadIdx.x;
    const int lane = tid & 63, wave = tid >> 6;            // wave in [0,8)
    const int wm = wave >> 1, wn = wave & 1;               // 4 x 2 wave grid
    const int l31 = lane & 31;                             // out row/col in tile
    const int kb  = lane >> 5;                             // k-half of each 64

    // chunk-exclusive XCD decode: id%8 == XCD (perf heuristic only)
    const int nblk = blockIdx.x;
    const int xcd = nblk & 7, bi = nblk >> 3;              // bi in [0,64)
    const int rb = bi & 15;                                // rowblk in [0,16)
    const int ch = (bi >> 4) + 4 * xcd;                    // chunk  in [0,32)
    const int row0  = rb * TM;
    const int cbase = ch * CHUNK;

    // A fragments, register-resident (32 VGPR): row row0+wm*32+l31, half kb
    i32x8 Areg[4];
    {
        const unsigned char* ar =
            A1 + (size_t)(row0 + wm * 32 + l31) * KTOT + kb * 32;
        #pragma unroll
        for (int ks = 0; ks < 4; ++ks) {
            const i32x4 lo = *(const i32x4*)(ar + ks * 64);
            const i32x4 hi = *(const i32x4*)(ar + ks * 64 + 16);
            Areg[ks] = __builtin_shufflevector(lo, hi, 0, 1, 2, 3, 4, 5, 6, 7);
        }
    }

    // per-tile B row base addresses (per-lane clamp for the >=NMEM tail)
    const int laneoff = wn * 64 + l31;
    const unsigned char* bA[2];
    auto computeBT = [&](int tile) {
        const int tb = cbase + tile * TN;
        #pragma unroll
        for (int tj = 0; tj < 2; ++tj) {
            int c = tb + laneoff + tj * 32;
            if (c > NMEM - 1) c = NMEM - 1;
            bA[tj] = B1 + ((size_t)c << 8) + kb * 32;
        }
    };
    auto loadB = [&](int ksOfs, i32x8* dst) {              // 4 dwordx4 loads
        #pragma unroll
        for (int tj = 0; tj < 2; ++tj) {
            const i32x4 lo = *(const i32x4*)(bA[tj] + ksOfs);
            const i32x4 hi = *(const i32x4*)(bA[tj] + ksOfs + 16);
            dst[tj] = __builtin_shufflevector(lo, hi, 0, 1, 2, 3, 4, 5, 6, 7);
        }
    };

    f32x16 acc[2];
    #pragma unroll
    for (int tj = 0; tj < 2; ++tj)
        #pragma unroll
        for (int r = 0; r < 16; ++r) acc[tj][r] = 0.f;

    i32x8 Bb[2], Bc[2];                                    // reg double buffer
    computeBT(0);
    loadB(0, Bb);

    for (int t = 0; t < CTILES; ++t) {
        // ks=0: prefetch ks1; MFMA ks0
        loadB(64, Bc);
        #pragma unroll
        for (int tj = 0; tj < 2; ++tj)
            acc[tj] = __builtin_amdgcn_mfma_scale_f32_32x32x64_f8f6f4(
                Areg[0], Bb[tj], acc[tj], 0, 0, 0, 0x7f7f7f7f, 0, 0x7f7f7f7f);
        // ks=1: prefetch ks2; MFMA ks1
        loadB(128, Bb);
        #pragma unroll
        for (int tj = 0; tj < 2; ++tj)
            acc[tj] = __builtin_amdgcn_mfma_scale_f32_32x32x64_f8f6f4(
                Areg[1], Bc[tj], acc[tj], 0, 0, 0, 0x7f7f7f7f, 0, 0x7f7f7f7f);
        // ks=2: prefetch ks3; MFMA ks2
        loadB(192, Bc);
        #pragma unroll
        for (int tj = 0; tj < 2; ++tj)
            acc[tj] = __builtin_amdgcn_mfma_scale_f32_32x32x64_f8f6f4(
                Areg[2], Bb[tj], acc[tj], 0, 0, 0, 0x7f7f7f7f, 0, 0x7f7f7f7f);
        // ks=3: prefetch next tile's ks0; MFMA ks3
        if (t + 1 < CTILES) { computeBT(t + 1); loadB(0, Bb); }
        #pragma unroll
        for (int tj = 0; tj < 2; ++tj)
            acc[tj] = __builtin_amdgcn_mfma_scale_f32_32x32x64_f8f6f4(
                Areg[3], Bc[tj], acc[tj], 0, 0, 0, 0x7f7f7f7f, 0, 0x7f7f7f7f);

        // epilogue: threshold + per-row global append (no LDS, no barrier)
        // 32x32 C/D: col = lane&31, row = (r&3) + 8*(r>>2) + 4*(lane>>5)
        const int tb = cbase + t * TN;
        const int rb0 = row0 + wm * 32 + 4 * kb;
        #pragma unroll
        for (int tj = 0; tj < 2; ++tj) {
            const int cidx = tb + wn * 64 + tj * 32 + l31;
            #pragma unroll
            for (int r = 0; r < 16; ++r) {
                const float v = acc[tj][r];
                if (v > THRS && cidx < NMEM) {
                    const int rg = rb0 + (r & 3) + 8 * (r >> 2);
                    const int pos = atomicAdd(&cnt[rg], 1);
                    if (pos < CAP)
                        cand_buf[(size_t)rg * CAP + pos] =
                            make_uint2(__float_as_uint(v * INV_XS),
                                       (unsigned)cidx);
                }
                acc[tj][r] = 0.f;                          // re-zero next tile
            }
        }
    }
}

// ---------------------------------------------------------------------------
// Phase C: per row — histogram k-select approx top-64 superset from the
// candidate list -> exact f32 recompute -> exact top-16 -> softmax ->
// scatter -> scale
// ---------------------------------------------------------------------------
__global__ __launch_bounds__(256) void knn_final(
    const int* __restrict__ cnt, const uint2* __restrict__ cand_buf,
    const float* __restrict__ xn, const float* __restrict__ mem,
    const int* __restrict__ labels, float* __restrict__ out)
{
    constexpr float BSCALE = 200.0f;                       // bucket = (v-THR)*200
    __shared__ float cls[NCLS];
    __shared__ uint2 cl[CAP];                              // 4 KB
    __shared__ int   hist[1024];                           // 4 KB
    __shared__ int   psum[256];
    __shared__ float tstar;
    __shared__ int   scount;
    __shared__ int   seli[SELCAP];
    __shared__ float ex[SELCAP];
    __shared__ float fs[TOPK];
    __shared__ int   fi[TOPK];
    __shared__ float zshare;

    const int row = blockIdx.x;
    const int tid = threadIdx.x;
    const int lane = tid & 63, w = tid >> 6;

    // query row quarter for this lane, register-resident (loop-invariant)
    const float4 xr = *(const float4*)(xn + (size_t)row * D + lane * 4);

    for (int c = tid; c < NCLS; c += 256) cls[c] = 0.f;
    for (int i = tid; i < 1024; i += 256) hist[i] = 0;
    int n = cnt[row]; if (n > CAP) n = CAP;
    for (int i = tid; i < n; i += 256) cl[i] = cand_buf[(size_t)row * CAP + i];
    if (tid == 0) scount = 0;
    __syncthreads();

    // histogram of approx sims
    for (int i = tid; i < n; i += 256) {
        const float v = __uint_as_float(cl[i].x);
        int b = (int)((v - THR) * BSCALE);
        b = max(0, min(1023, b));
        atomicAdd(&hist[b], 1);
    }
    __syncthreads();
    psum[tid] = hist[4 * tid] + hist[4 * tid + 1] + hist[4 * tid + 2] + hist[4 * tid + 3];
    __syncthreads();
    if (tid == 0) {
        // threshold t* = lower edge of the bucket where top-count crosses MSEL
        int cum = 0, g = 255;
        for (; g >= 0; --g) {
            if (cum + psum[g] >= MSEL) break;
            cum += psum[g];
        }
        float t = THR;                                     // fallback: all
        if (g >= 0) {
            int bb = 4 * g + 3;
            for (; bb > 4 * g; --bb) {
                cum += hist[bb];
                if (cum >= MSEL) break;
            }
            if (bb == 4 * g) cum += hist[bb];              // ensured >= MSEL
            t = THR + (float)bb * (1.0f / BSCALE);
        }
        tstar = t;
    }
    __syncthreads();
    // collect superset (count in [MSEL, MSEL+few])
    for (int i = tid; i < n; i += 256) {
        const float v = __uint_as_float(cl[i].x);
        if (v >= tstar) {
            const int p = atomicAdd(&scount, 1);
            if (p < SELCAP) seli[p] = (int)cl[i].y;
        }
    }
    __syncthreads();
    int ns = scount; if (ns > SELCAP) ns = SELCAP;

    // exact f32 recompute: wave w handles candidates w, w+4, ...
    for (int c = w; c < ns; c += 4) {
        const float4 mv = *(const float4*)(mem + (size_t)seli[c] * D + lane * 4);
        float s = xr.x * mv.x + xr.y * mv.y + xr.z * mv.z + xr.w * mv.w;
        #pragma unroll
        for (int off = 32; off > 0; off >>= 1) s += __shfl_down(s, off, 64);
        if (lane == 0) ex[c] = s;
    }
    __syncthreads();

    if (tid == 0) {
        // exact top-16 of the <=96 refined candidates
        float kmin = NEG; int kslot = 0;
        #pragma unroll
        for (int s = 0; s < TOPK; ++s) { fs[s] = NEG; fi[s] = -1; }
        for (int c = 0; c < ns; ++c) {
            const float v = ex[c];
            if (v > kmin) {
                fs[kslot] = v; fi[kslot] = seli[c];
                kmin = fs[0]; kslot = 0;
                #pragma unroll
                for (int s = 1; s < TOPK; ++s) {
                    const float tq = fs[s];
                    if (tq < kmin) { kmin = tq; kslot = s; }
                }
            }
        }
        float smax = fs[0];
        #pragma unroll
        for (int s = 1; s < TOPK; ++s) smax = fmaxf(smax, fs[s]);
        float e[TOPK]; float Z = 0.f;
        #pragma unroll
        for (int s = 0; s < TOPK; ++s) {
            e[s] = (fi[s] >= 0) ? expf((fs[s] - smax) * (1.0f / TAU)) : 0.f;
            Z += e[s];
        }
        for (int s = 0; s < TOPK; ++s) {
            if (fi[s] >= 0) cls[labels[fi[s]]] += e[s];    // serial: dup labels safe
        }
        zshare = Z;
    }
    __syncthreads();
    const float scale = LOGIT_SCALE / zshare;
    for (int c = tid; c < NCLS; c += 256)
        out[(size_t)row * NCLS + c] = cls[c] * scale;
}

// ---------------------------------------------------------------------------
extern "C" void kernel_launch(void* const* d_in, const int* in_sizes, int n_in,
                              void* d_out, int out_size, void* d_ws, size_t ws_size,
                              hipStream_t stream) {
    (void)in_sizes; (void)n_in; (void)out_size; (void)ws_size;
    const float* x    = (const float*)d_in[0];
    const float* mean = (const float*)d_in[1];
    const float* stdv = (const float*)d_in[2];
    const float* mem  = (const float*)d_in[3];
    const int*   lbl  = (const int*)d_in[4];
    float* out = (float*)d_out;

    // ws: A1 0.5 MB | XN 2 MB | B1 25.6 MB | cnt 8 KB | cand 8.4 MB
    unsigned char* A1 = (unsigned char*)d_ws;
    float* XN = (float*)(A1 + (size_t)BQ * KTOT);
    unsigned char* B1 = (unsigned char*)(XN + (size_t)BQ * D);
    int* cnt = (int*)(B1 + (size_t)NMEM * KTOT);
    uint2* cand = (uint2*)(cnt + BQ);

    knn_prep<<<BQ, 256, 0, stream>>>(x, mean, stdv, A1, XN, cnt);
    knn_convb<<<(NMEM + 7) / 8, 256, 0, stream>>>(mem, B1);
    knn_gemm_topk<<<NBLK, 512, 0, stream>>>(A1, B1, cnt, cand);
    knn_final<<<BQ, 256, 0, stream>>>(cnt, cand, XN, mem, lbl, out);
}

// Round 11
// 371.579 us; speedup vs baseline: 1.2565x; 1.2565x over previous
//
#include <hip/hip_runtime.h>
#include <math.h>

// Problem constants
constexpr int BQ   = 2048;
constexpr int D    = 256;
constexpr int NMEM = 100000;
constexpr int TOPK = 16;
constexpr int NCLS = 1000;
constexpr float TAU = 0.2f;
constexpr float LOGIT_SCALE = 20.0f;

// fp8(e4m3) GEMM (K=256) for candidate SELECTION only, via 2x-rate
// mfma_scale_f32_32x32x64_f8f6f4 (scales pinned to 1.0 = e8m0 0x7f).
// r10 lesson: barrier-free global->reg B streaming is UNCOALESCED (each
// lane a different row => 32 lines/half-wave; FETCH 37 MB, MfmaUtil 8%)
// and spilled (WRITE 52 MB). REVERTED to the r6 LDS pipeline (coalesced
// 64-B granule staging, proven 156 us) with two orthogonal changes:
//  * 8 waves x 32x64-per-wave (same 128x128 block tile): acc 64->32 AGPR
//    => ~92 regs => (512,4) legal => 16 waves/CU (r6: 12). Attacks the
//    ~50% SIMD idle seen in r6's cycle budget.
//  * 4-deep LDS buffers (64 KB): counted vmcnt waits on loads issued TWO
//    iterations back (~3000 cyc >> 900 cyc HBM) - the wait is truly free.
constexpr int KTOT = 256;        // k-elements (= bytes in fp8)
constexpr int BK   = 64;         // k per k-step (64 B/row, 8 KB tile)
constexpr int TM   = 128;
constexpr int TN   = 128;
constexpr int CTILES = 25;
constexpr int CHUNK  = TN * CTILES;               // 3200
constexpr int NCH    = 32;                        // 32*3200 = 102400 >= 100000
constexpr int RBLK   = BQ / TM;                   // 16
constexpr int NBLK   = RBLK * NCH;                // 512 = 2 blocks/CU exact
constexpr int TOTAL_IT = CTILES * (KTOT / BK);    // 100
constexpr float XSCALE = 16.0f;
constexpr float INV_XS = 0.0625f;
constexpr float THR    = 3.0f;   // candidate floor (mean ~136/row above it)
constexpr float THRS   = 48.0f;  // THR * XSCALE (raw acc scale)
constexpr int CAP    = 512;      // per-row candidate cap
constexpr int MSEL   = 64;       // refinement superset target
constexpr int SELCAP = 96;
constexpr float NEG  = -3.0e38f;

using i32x4  = __attribute__((ext_vector_type(4))) int;
using i32x8  = __attribute__((ext_vector_type(8))) int;
using f32x16 = __attribute__((ext_vector_type(16))) float;

// f32 -> OCP e4m3 (RNE, clamp to 448, flush subnormals — inputs pre-scaled
// so the flush region carries negligible mass).
__device__ __forceinline__ unsigned f2e4m3(float f) {
    const unsigned u = __float_as_uint(f);
    const unsigned s = (u >> 24) & 0x80u;
    const int e = (int)((u >> 23) & 0xff);
    int te = e - 120;                          // e4m3 exponent field (bias 7)
    if (te <= 0) return s;                     // flush tiny
    const unsigned m = u & 0x7fffffu;
    const unsigned r = m + 0x7ffffu + ((m >> 20) & 1u);
    unsigned keep;
    if (r & 0x800000u) { ++te; keep = 0; } else keep = (r >> 20) & 7u;
    if (te >= 16 || (te == 15 && keep == 7)) return s | 0x7eu;  // clamp 448
    return s | ((unsigned)te << 3) | keep;
}

__device__ __forceinline__ void load_lds16(const void* g, void* l) {
    __builtin_amdgcn_global_load_lds((const __attribute__((address_space(1))) void*)g,
                                     (__attribute__((address_space(3))) void*)l,
                                     16, 0, 0);
}

// ---------------------------------------------------------------------------
// Phase A: standardize + L2-normalize; emit A1 = e4m3(16*x_hat), XN = f32
// x_hat, and zero the per-row candidate counters.
// ---------------------------------------------------------------------------
__global__ __launch_bounds__(256) void knn_prep(
    const float* __restrict__ x, const float* __restrict__ mean,
    const float* __restrict__ stdv, unsigned char* __restrict__ A1,
    float* __restrict__ XN, int* __restrict__ cnt)
{
    const int row = blockIdx.x;
    const int t = threadIdx.x;                       // feature index, D==256
    float v = (x[row * D + t] - mean[t]) / stdv[t];
    float s = v * v;
    #pragma unroll
    for (int off = 32; off > 0; off >>= 1) s += __shfl_down(s, off, 64);
    __shared__ float wsum[4];
    __shared__ float nrm;
    const int lane = t & 63, wid = t >> 6;
    if (lane == 0) wsum[wid] = s;
    __syncthreads();
    if (t == 0) {
        nrm = fmaxf(sqrtf(wsum[0] + wsum[1] + wsum[2] + wsum[3]), 1e-6f);
        cnt[row] = 0;
    }
    __syncthreads();
    const float xnv = v / nrm;
    A1[(size_t)row * KTOT + t] = (unsigned char)f2e4m3(xnv * XSCALE);
    XN[(size_t)row * D + t] = xnv;
}

// ---------------------------------------------------------------------------
// Phase A2: mem_features -> B1 = e4m3(mem); 8 rows/block, float4 -> 8 bytes
// ---------------------------------------------------------------------------
__global__ __launch_bounds__(256) void knn_convb(
    const float* __restrict__ mem, unsigned char* __restrict__ B1)
{
    const int tid = threadIdx.x;
    const int rloc = tid >> 5, t = tid & 31;         // 32 threads per row
    const long n = (long)blockIdx.x * 8 + rloc;
    if (n >= NMEM) return;
    const float* src = mem + n * D + t * 8;
    const float4 v0 = *(const float4*)(src);
    const float4 v1 = *(const float4*)(src + 4);
    const float f[8] = {v0.x, v0.y, v0.z, v0.w, v1.x, v1.y, v1.z, v1.w};
    unsigned long long pk = 0;
    #pragma unroll
    for (int i = 0; i < 8; ++i)
        pk |= (unsigned long long)f2e4m3(f[i]) << (8 * i);
    *(unsigned long long*)(B1 + n * KTOT + t * 8) = pk;
}

// ---------------------------------------------------------------------------
// Phase B: 4-deep pipelined MX-fp8 GEMM, 8 waves x (32 rows x 64 cols).
// Per step g (buf = g%4 = ks, compile-time in the unrolled body):
//   [6x ds_read_b128 frags from buf ks] [issue stage(g+3) -> buf (ks+3)&3]
//   [2 MFMA] [epilogue if ks==3] [s_waitcnt vmcnt(4)] [s_barrier].
//  * stage = 1 A granule + 1 B granule per thread (512 thr x 16 B = both
//    8-KB tiles), coalesced 64-B per row quad — the r6-proven path.
//  * vmcnt(4): outstanding = stage(g+1),(g+2),(g+3) x2 = 6 -> wait to 4
//    drains stage(g+1), issued TWO iters earlier. Tail: vmcnt(2)/(0).
//  * WAR: stage(g+3) writes buf (g-1)%4, whose readers finished before
//    barrier(g-1->g). RAW: every thread drains g+1 before its barrier.
//  * regs ~60 VGPR + 32 AGPR < 128 cap. TRIPWIRE: WRITE_SIZE > 35 MB =>
//    spill => revert to exact r6.
// ---------------------------------------------------------------------------
__global__ __launch_bounds__(512, 4) void knn_gemm_topk(
    const unsigned char* __restrict__ A1, const unsigned char* __restrict__ B1,
    int* __restrict__ cnt, uint2* __restrict__ cand_buf)
{
    __shared__ alignas(16) unsigned char As[4][TM * BK];   // 4 x 8 KB
    __shared__ alignas(16) unsigned char Bs[4][TN * BK];   // 4 x 8 KB

    const int tid  = threadIdx.x;
    const int lane = tid & 63, wave = tid >> 6;            // wave in [0,8)
    const int wm = wave >> 1, wn = wave & 1;               // 4 x 2 wave grid
    const int l31 = lane & 31;                             // out row/col in tile
    const int kb  = lane >> 5;                             // k-half of BK=64

    // chunk-exclusive XCD decode: id%8 == XCD (perf heuristic only)
    const int nblk = blockIdx.x;
    const int xcd = nblk & 7, bi = nblk >> 3;              // bi in [0,64)
    const int rb = bi & 15;                                // rowblk in [0,16)
    const int ch = (bi >> 4) + 4 * xcd;                    // chunk  in [0,32)
    const int row0  = rb * TM;
    const int cbase = ch * CHUNK;

    // frag byte offsets (k-loop invariant). lane reads granules
    // (row, 2*kb+c); phys seg = ((2*kb+c) - (row>>1)) & 3.
    const int ra = wm * 32 + l31;                          // A row of this lane
    int aoff[2], boff[2][2];
    #pragma unroll
    for (int c = 0; c < 2; ++c)
        aoff[c] = ra * BK + (((2 * kb + c) - (ra >> 1)) & 3) * 16;
    #pragma unroll
    for (int tj = 0; tj < 2; ++tj) {
        const int br = wn * 64 + tj * 32 + l31;
        #pragma unroll
        for (int c = 0; c < 2; ++c)
            boff[tj][c] = br * BK + (((2 * kb + c) - (br >> 1)) & 3) * 16;
    }

    // per-thread staging geometry: thread stages A granule tid and B
    // granule tid (row r = tid>>2, slot sl = tid&3, rotated seg).
    const int r  = tid >> 2, sl = tid & 3;
    const int seg = ((sl + (r >> 1)) & 3) << 4;
    const unsigned char* aSrc = A1 + (size_t)(row0 + r) * KTOT + seg;
    const unsigned char* bB;                               // per-tile B src
    auto computeBB = [&](int tile) {
        int cand = cbase + tile * TN + r;
        if (cand >= NMEM) cand = NMEM - 1;
        bB = B1 + ((size_t)cand << 8) + seg;
    };
    auto stage = [&](int buf, int kofs) {                  // 2 loads/thread
        load_lds16(aSrc + kofs, (char*)As[buf] + wave * 1024);
        load_lds16(bB + kofs, (char*)Bs[buf] + wave * 1024);
    };

    f32x16 acc[2];
    #pragma unroll
    for (int tj = 0; tj < 2; ++tj)
        #pragma unroll
        for (int q = 0; q < 16; ++q) acc[tj][q] = 0.f;

    // prologue: stage steps 0,1,2 (tile 0, kofs 0/64/128); drain step 0
    computeBB(0);
    stage(0, 0);
    stage(1, 64);
    stage(2, 128);
    asm volatile("s_waitcnt vmcnt(4)" ::: "memory");
    __builtin_amdgcn_sched_barrier(0);
    __builtin_amdgcn_s_barrier();

    for (int t = 0; t < CTILES; ++t) {
        #pragma unroll
        for (int ks = 0; ks < 4; ++ks) {                   // buf = ks (const)
            const int g = t * 4 + ks;

            // 1) frag ds_reads from buf ks
            const unsigned char* Ab = As[ks];
            const unsigned char* Bb = Bs[ks];
            const i32x4 alo = *(const i32x4*)(Ab + aoff[0]);
            const i32x4 ahi = *(const i32x4*)(Ab + aoff[1]);
            const i32x8 Afr =
                __builtin_shufflevector(alo, ahi, 0, 1, 2, 3, 4, 5, 6, 7);
            i32x8 Bfr[2];
            #pragma unroll
            for (int tj = 0; tj < 2; ++tj) {
                const i32x4 blo = *(const i32x4*)(Bb + boff[tj][0]);
                const i32x4 bhi = *(const i32x4*)(Bb + boff[tj][1]);
                Bfr[tj] =
                    __builtin_shufflevector(blo, bhi, 0, 1, 2, 3, 4, 5, 6, 7);
            }

            // 2) issue stage(g+3) into buf (ks+3)&3; new tile starts at ks==1
            if (g + 3 < TOTAL_IT) {
                if (ks == 1) computeBB(t + 1);
                stage((ks + 3) & 3, ((ks + 3) & 3) << 6);
            }

            // 3) MFMA: 1x2 out-tiles of 32x32, K=64 per instruction
            #pragma unroll
            for (int tj = 0; tj < 2; ++tj)
                acc[tj] = __builtin_amdgcn_mfma_scale_f32_32x32x64_f8f6f4(
                    Afr, Bfr[tj], acc[tj], 0, 0,
                    0, 0x7f7f7f7f, 0, 0x7f7f7f7f);

            // 4) epilogue at tile end (acc + global atomics only; no LDS)
            if (ks == 3) {
                const int tb = cbase + t * TN;
                // 32x32 C/D: col=lane&31, row=(q&3)+8*(q>>2)+4*(lane>>5)
                const int rb0 = row0 + wm * 32 + 4 * kb;
                #pragma unroll
                for (int tj = 0; tj < 2; ++tj) {
                    const int cidx = tb + wn * 64 + tj * 32 + l31;
                    #pragma unroll
                    for (int q = 0; q < 16; ++q) {
                        const float v = acc[tj][q];
                        if (v > THRS && cidx < NMEM) {
                            const int rg = rb0 + (q & 3) + 8 * (q >> 2);
                            const int pos = atomicAdd(&cnt[rg], 1);
                            if (pos < CAP)
                                cand_buf[(size_t)rg * CAP + pos] =
                                    make_uint2(__float_as_uint(v * INV_XS),
                                               (unsigned)cidx);
                        }
                        acc[tj][q] = 0.f;                  // re-zero next tile
                    }
                }
            }

            // 5) counted wait + raw barrier (steady state never drains)
            if (g + 1 < TOTAL_IT) {
                if (g + 3 < TOTAL_IT) {
                    asm volatile("s_waitcnt vmcnt(4)" ::: "memory");
                } else if (g + 2 < TOTAL_IT) {
                    asm volatile("s_waitcnt vmcnt(2)" ::: "memory");
                } else {
                    asm volatile("s_waitcnt vmcnt(0)" ::: "memory");
                }
                __builtin_amdgcn_sched_barrier(0);
                __builtin_amdgcn_s_barrier();
            }
        }
    }
}

// ---------------------------------------------------------------------------
// Phase C: per row — histogram k-select approx top-64 superset from the
// candidate list -> exact f32 recompute -> exact top-16 -> softmax ->
// scatter -> scale
// ---------------------------------------------------------------------------
__global__ __launch_bounds__(256) void knn_final(
    const int* __restrict__ cnt, const uint2* __restrict__ cand_buf,
    const float* __restrict__ xn, const float* __restrict__ mem,
    const int* __restrict__ labels, float* __restrict__ out)
{
    constexpr float BSCALE = 200.0f;                       // bucket = (v-THR)*200
    __shared__ float cls[NCLS];
    __shared__ uint2 cl[CAP];                              // 4 KB
    __shared__ int   hist[1024];                           // 4 KB
    __shared__ int   psum[256];
    __shared__ float tstar;
    __shared__ int   scount;
    __shared__ int   seli[SELCAP];
    __shared__ float ex[SELCAP];
    __shared__ float fs[TOPK];
    __shared__ int   fi[TOPK];
    __shared__ float zshare;

    const int row = blockIdx.x;
    const int tid = threadIdx.x;
    const int lane = tid & 63, w = tid >> 6;

    // query row quarter for this lane, register-resident (loop-invariant)
    const float4 xr = *(const float4*)(xn + (size_t)row * D + lane * 4);

    for (int c = tid; c < NCLS; c += 256) cls[c] = 0.f;
    for (int i = tid; i < 1024; i += 256) hist[i] = 0;
    int n = cnt[row]; if (n > CAP) n = CAP;
    for (int i = tid; i < n; i += 256) cl[i] = cand_buf[(size_t)row * CAP + i];
    if (tid == 0) scount = 0;
    __syncthreads();

    // histogram of approx sims
    for (int i = tid; i < n; i += 256) {
        const float v = __uint_as_float(cl[i].x);
        int b = (int)((v - THR) * BSCALE);
        b = max(0, min(1023, b));
        atomicAdd(&hist[b], 1);
    }
    __syncthreads();
    psum[tid] = hist[4 * tid] + hist[4 * tid + 1] + hist[4 * tid + 2] + hist[4 * tid + 3];
    __syncthreads();
    if (tid == 0) {
        // threshold t* = lower edge of the bucket where top-count crosses MSEL
        int cum = 0, g = 255;
        for (; g >= 0; --g) {
            if (cum + psum[g] >= MSEL) break;
            cum += psum[g];
        }
        float t = THR;                                     // fallback: all
        if (g >= 0) {
            int bb = 4 * g + 3;
            for (; bb > 4 * g; --bb) {
                cum += hist[bb];
                if (cum >= MSEL) break;
            }
            if (bb == 4 * g) cum += hist[bb];              // ensured >= MSEL
            t = THR + (float)bb * (1.0f / BSCALE);
        }
        tstar = t;
    }
    __syncthreads();
    // collect superset (count in [MSEL, MSEL+few])
    for (int i = tid; i < n; i += 256) {
        const float v = __uint_as_float(cl[i].x);
        if (v >= tstar) {
            const int p = atomicAdd(&scount, 1);
            if (p < SELCAP) seli[p] = (int)cl[i].y;
        }
    }
    __syncthreads();
    int ns = scount; if (ns > SELCAP) ns = SELCAP;

    // exact f32 recompute: wave w handles candidates w, w+4, ...
    for (int c = w; c < ns; c += 4) {
        const float4 mv = *(const float4*)(mem + (size_t)seli[c] * D + lane * 4);
        float s = xr.x * mv.x + xr.y * mv.y + xr.z * mv.z + xr.w * mv.w;
        #pragma unroll
        for (int off = 32; off > 0; off >>= 1) s += __shfl_down(s, off, 64);
        if (lane == 0) ex[c] = s;
    }
    __syncthreads();

    if (tid == 0) {
        // exact top-16 of the <=96 refined candidates
        float kmin = NEG; int kslot = 0;
        #pragma unroll
        for (int s = 0; s < TOPK; ++s) { fs[s] = NEG; fi[s] = -1; }
        for (int c = 0; c < ns; ++c) {
            const float v = ex[c];
            if (v > kmin) {
                fs[kslot] = v; fi[kslot] = seli[c];
                kmin = fs[0]; kslot = 0;
                #pragma unroll
                for (int s = 1; s < TOPK; ++s) {
                    const float tq = fs[s];
                    if (tq < kmin) { kmin = tq; kslot = s; }
                }
            }
        }
        float smax = fs[0];
        #pragma unroll
        for (int s = 1; s < TOPK; ++s) smax = fmaxf(smax, fs[s]);
        float e[TOPK]; float Z = 0.f;
        #pragma unroll
        for (int s = 0; s < TOPK; ++s) {
            e[s] = (fi[s] >= 0) ? expf((fs[s] - smax) * (1.0f / TAU)) : 0.f;
            Z += e[s];
        }
        for (int s = 0; s < TOPK; ++s) {
            if (fi[s] >= 0) cls[labels[fi[s]]] += e[s];    // serial: dup labels safe
        }
        zshare = Z;
    }
    __syncthreads();
    const float scale = LOGIT_SCALE / zshare;
    for (int c = tid; c < NCLS; c += 256)
        out[(size_t)row * NCLS + c] = cls[c] * scale;
}

// ---------------------------------------------------------------------------
extern "C" void kernel_launch(void* const* d_in, const int* in_sizes, int n_in,
                              void* d_out, int out_size, void* d_ws, size_t ws_size,
                              hipStream_t stream) {
    (void)in_sizes; (void)n_in; (void)out_size; (void)ws_size;
    const float* x    = (const float*)d_in[0];
    const float* mean = (const float*)d_in[1];
    const float* stdv = (const float*)d_in[2];
    const float* mem  = (const float*)d_in[3];
    const int*   lbl  = (const int*)d_in[4];
    float* out = (float*)d_out;

    // ws: A1 0.5 MB | XN 2 MB | B1 25.6 MB | cnt 8 KB | cand 8.4 MB
    unsigned char* A1 = (unsigned char*)d_ws;
    float* XN = (float*)(A1 + (size_t)BQ * KTOT);
    unsigned char* B1 = (unsigned char*)(XN + (size_t)BQ * D);
    int* cnt = (int*)(B1 + (size_t)NMEM * KTOT);
    uint2* cand = (uint2*)(cnt + BQ);

    knn_prep<<<BQ, 256, 0, stream>>>(x, mean, stdv, A1, XN, cnt);
    knn_convb<<<(NMEM + 7) / 8, 256, 0, stream>>>(mem, B1);
    knn_gemm_topk<<<NBLK, 512, 0, stream>>>(A1, B1, cnt, cand);
    knn_final<<<BQ, 256, 0, stream>>>(cnt, cand, XN, mem, lbl, out);
}